// Round 10
// baseline (236.719 us; speedup 1.0000x reference)
//
#include <hip/hip_runtime.h>

#define BATCH 8
#define NPOS 784          // H*W per batch
#define CH 512
#define DI 4096
#define PPC 4             // positions per chunk (multiple of 2)
#define CHUNKS (NPOS / PPC)   // 196 -> 1568 blocks
#define PHI_LEN 8705      // 1 + 512 + 2*4096
#define REP 16            // accumulator replicas (contention / 16)
#define S_STRIDE (BATCH * 2 * 2049 * 2)       // floats per spectral replica
#define S_FLOATS (REP * S_STRIDE)
#define FO_OFF S_FLOATS                        // first-order replicas
#define FO_STRIDE (BATCH * CH)
#define FO_FLOATS (REP * FO_STRIDE)
#define PH_OFF (FO_OFF + FO_FLOATS)            // stage2 output [b][2][4096]
#define ZERO_FLOATS (S_FLOATS + FO_FLOATS)

__device__ __forceinline__ float2 cmul(float2 a, float2 b) {
  return make_float2(a.x * b.x - a.y * b.y, a.x * b.y + a.y * b.x);
}
__device__ __forceinline__ float2 f2add(float2 a, float2 b) {
  return make_float2(a.x + b.x, a.y + b.y);
}
__device__ __forceinline__ float2 f2sub(float2 a, float2 b) {
  return make_float2(a.x - b.x, a.y - b.y);
}

// forward DFT4 (w4 = -i), natural order out
__device__ __forceinline__ void dft4(float2& a, float2& b, float2& c, float2& d) {
  float t0x = a.x + c.x, t0y = a.y + c.y;
  float t1x = a.x - c.x, t1y = a.y - c.y;
  float t2x = b.x + d.x, t2y = b.y + d.y;
  float t3x = b.x - d.x, t3y = b.y - d.y;
  a = make_float2(t0x + t2x, t0y + t2y);
  c = make_float2(t0x - t2x, t0y - t2y);
  b = make_float2(t1x + t3y, t1y - t3x);   // t1 - i*t3
  d = make_float2(t1x - t3y, t1y + t3x);   // t1 + i*t3
}

// forward 8-point DFT, natural in, natural out
__device__ __forceinline__ void dft8(float2 v[8]) {
  float2 e0 = v[0], e1 = v[2], e2 = v[4], e3 = v[6];
  dft4(e0, e1, e2, e3);
  float2 o0 = v[1], o1 = v[3], o2 = v[5], o3 = v[7];
  dft4(o0, o1, o2, o3);
  const float r = 0.70710678118654752f;
  o1 = make_float2(r * (o1.x + o1.y), r * (o1.y - o1.x));   // *w8^1
  o2 = make_float2(o2.y, -o2.x);                            // *-i
  o3 = make_float2(r * (o3.y - o3.x), -r * (o3.x + o3.y));  // *w8^3
  v[0] = f2add(e0, o0); v[4] = f2sub(e0, o0);
  v[1] = f2add(e1, o1); v[5] = f2sub(e1, o1);
  v[2] = f2add(e2, o2); v[6] = f2sub(e2, o2);
  v[3] = f2add(e3, o3); v[7] = f2sub(e3, o3);
}

// v[u] *= w^u, u=0..7
__device__ __forceinline__ void twiddle8(float2 v[8], float2 w) {
  float2 w2 = cmul(w, w);
  float2 w3 = cmul(w2, w);
  float2 w4 = cmul(w2, w2);
  v[1] = cmul(v[1], w);
  v[2] = cmul(v[2], w2);
  v[3] = cmul(v[3], w3);
  v[4] = cmul(v[4], w4);
  v[5] = cmul(v[5], cmul(w4, w));
  v[6] = cmul(v[6], cmul(w4, w2));
  v[7] = cmul(v[7], cmul(w4, w3));
}

// Hermitian pair product + chain update (Zk = spectrum[k], Zm = spectrum[4096-k])
template <int MODE>
__device__ __forceinline__ void prodpair(float2 Zk, float2 Zm, float2& carry,
                                         float2& acc2, float2& acc3) {
  float2 E = make_float2(0.5f * (Zk.x + Zm.x), 0.5f * (Zk.y - Zm.y));
  float2 O = make_float2(0.5f * (Zk.y + Zm.y), -0.5f * (Zk.x - Zm.x));
  if (MODE == 0) {
    float2 P = cmul(E, O);
    carry = P;
    acc2.x += P.x; acc2.y += P.y;
  } else if (MODE == 1) {
    float2 P3 = cmul(carry, E);
    acc3.x += P3.x; acc3.y += P3.y;
    carry = O;
  } else {
    float2 P = cmul(carry, E);
    acc2.x += P.x; acc2.y += P.y;
    float2 P3 = cmul(P, O);
    acc3.x += P3.x; acc3.y += P3.y;
  }
}
template <int MODE>
__device__ __forceinline__ void nyq(float2 Zq, float& carryx, float& acc2x,
                                    float& acc3x) {
  if (MODE == 0) { carryx = Zq.x * Zq.y; acc2x += carryx; }
  else if (MODE == 1) { acc3x += carryx * Zq.x; carryx = Zq.y; }
  else { float tt = carryx * Zq.x; acc2x += tt; acc3x += tt * Zq.y; }
}

// ---- stages 0-2: wave-local on butterfly t (verified R8/R9) ----
__device__ __forceinline__ void s0w(float2* Z, int t) {
  const int base = t << 3;
  const int m0 = (t >> 1) & 15;
  float2 v[8];
  #pragma unroll
  for (int u = 0; u < 8; ++u) v[u] = Z[(base + u) ^ m0];
  dft8(v);
  #pragma unroll
  for (int k = 0; k < 8; ++k) Z[(base + k) ^ m0] = v[k];
}
__device__ __forceinline__ void s1w(float2* Z, int t, float2 w) {
  const int base = ((t >> 3) << 6) + (t & 7);
  const int g4 = (t >> 3) << 2;
  float2 v[8];
  #pragma unroll
  for (int u = 0; u < 8; ++u)
    v[u] = Z[(base + (u << 3)) ^ ((g4 + (u >> 1)) & 15)];
  twiddle8(v, w);
  dft8(v);
  #pragma unroll
  for (int k = 0; k < 8; ++k)
    Z[(base + (k << 3)) ^ ((g4 + (k >> 1)) & 15)] = v[k];
}
__device__ __forceinline__ void s2w(float2* Z, int t, float2 w) {
  const int base = ((t >> 6) << 9) + (t & 63);
  const int jh = (t & 63) >> 4;
  float2 v[8];
  #pragma unroll
  for (int u = 0; u < 8; ++u)
    v[u] = Z[(base + (u << 6)) ^ (((u << 2) + jh) & 15)];
  twiddle8(v, w);
  dft8(v);
  #pragma unroll
  for (int k = 0; k < 8; ++k)
    Z[(base + (k << 6)) ^ (((k << 2) + jh) & 15)] = v[k];
}

// ---- stage 3 on remapped butterfly g + in-register Hermitian product.
// Pairing: lane l<32 holds g=32w+l, lane l+32 holds 512-g -> partner via
// __shfl_xor(.,32). Reads+zeroes its own 8 inputs (owner-exclusive). ----
template <int MODE>
__device__ __forceinline__ void s3prod(float2* Z, int g, float2 wG,
                                       bool selfp, float2 carry[4],
                                       float2 acc2[4], float2 acc3[4],
                                       float& carryx, float& acc2x,
                                       float& acc3x) {
  const int mg = (g >> 4) & 15;
  float2 v[8];
  #pragma unroll
  for (int u = 0; u < 8; ++u) v[u] = Z[(g + (u << 9)) ^ mg];
  #pragma unroll
  for (int u = 0; u < 8; ++u) Z[(g + (u << 9)) ^ mg] = make_float2(0.f, 0.f);
  twiddle8(v, wG);
  dft8(v);
  // partner spectrum values: partner butterfly's slot 7-r, r=0..3
  float2 pv[4];
  #pragma unroll
  for (int r = 0; r < 4; ++r) {
    pv[r].x = __shfl_xor(v[7 - r].x, 32);
    pv[r].y = __shfl_xor(v[7 - r].y, 32);
  }
  if (selfp) {
    // butterfly 0 (g==0): partner slots (8-r)&7; butterfly 256: own 7-r
    if (g == 0) {
      pv[0] = v[0]; pv[1] = v[7]; pv[2] = v[6]; pv[3] = v[5];
    } else {
      pv[0] = v[7]; pv[1] = v[6]; pv[2] = v[5]; pv[3] = v[4];
    }
  }
  #pragma unroll
  for (int r = 0; r < 4; ++r)
    prodpair<MODE>(v[r], pv[r], carry[r], acc2[r], acc3[r]);
  if (g == 0) nyq<MODE>(v[4], carryx, acc2x, acc3x);  // bin 2048
}

__global__ __launch_bounds__(512) void cbp_stage1(
    const float* __restrict__ x, const float* __restrict__ alpha,
    const int* __restrict__ h_idx, const int* __restrict__ s_bits,
    float* __restrict__ ws) {
  __shared__ float2 Z[DI];
  float* Zf = (float*)Z;
  const int t = threadIdx.x;
  const int w = t >> 6, l = t & 63;
  const int bb = blockIdx.x / CHUNKS;
  const int ch = blockIdx.x % CHUNKS;
  const int rep = blockIdx.x & (REP - 1);

  // stage-3 butterfly assignment (pairs within wave, partner = lane^32)
  int g;
  if (l < 32) g = 32 * w + l;
  else if (w == 0 && l == 32) g = 256;
  else g = 544 - 32 * w - l;   // 512 - (32w + (l-32))
  const bool selfp = (w == 0) && ((l & 31) == 0);

  // hash -> phys(digitrev8(h)); sign packed in top bit (set == flip)
  auto mapq = [](int h, int s) {
    int r = ((h & 7) << 9) | (((h >> 3) & 7) << 6) | (((h >> 6) & 7) << 3) |
            (h >> 9);
    return (r ^ ((r >> 4) & 15)) | ((s ^ 1) << 31);
  };
  auto sgn = [](float v, int p) {
    return __int_as_float(__float_as_int(v) ^ ((unsigned)p & 0x80000000u));
  };
  const int q0 = mapq(h_idx[t], s_bits[t]);
  const int q1 = mapq(h_idx[CH + t], s_bits[CH + t]);
  const int q2 = mapq(h_idx[2 * CH + t], s_bits[2 * CH + t]);

  float sv_, cv_;
  __sincosf(-9.8174770424681038e-2f * (float)(t & 7), &sv_, &cv_);   // -2pi/64*j
  const float2 w1b = make_float2(cv_, sv_);
  __sincosf(-1.2271846303085130e-2f * (float)(t & 63), &sv_, &cv_);  // -2pi/512*j
  const float2 w2b = make_float2(cv_, sv_);
  __sincosf(-1.5339807878856412e-3f * (float)g, &sv_, &cv_);         // -2pi/4096*g
  const float2 wG = make_float2(cv_, sv_);

  float2 acc2[4], acc3[4], carry[4];
  #pragma unroll
  for (int j = 0; j < 4; ++j) {
    acc2[j] = make_float2(0.f, 0.f);
    acc3[j] = make_float2(0.f, 0.f);
  }
  float acc2x = 0.f, acc3x = 0.f, carryx = 0.f;
  float xs = 0.f;

  #pragma unroll
  for (int q = 0; q < 8; ++q) Z[t + (q << 9)] = make_float2(0.f, 0.f);
  __syncthreads();

  for (int ip = 0; ip < PPC / 2; ++ip) {
    const int n0 = bb * NPOS + ch * PPC + ip * 2;
    const float xv0 = x[(size_t)n0 * CH + t];
    const float xv1 = x[(size_t)(n0 + 1) * CH + t];
    xs += xv0 + xv1;

    // ---- FFT1: sk0(n) + i*sk1(n) ----
    atomicAdd(&Zf[2 * (q0 & 0xFFF)], sgn(xv0, q0));
    atomicAdd(&Zf[2 * (q1 & 0xFFF) + 1], sgn(xv0, q1));
    __syncthreads();
    s0w(Z, t);
    __builtin_amdgcn_wave_barrier();
    s1w(Z, t, w1b);
    __builtin_amdgcn_wave_barrier();
    s2w(Z, t, w2b);
    __syncthreads();
    s3prod<0>(Z, g, wG, selfp, carry, acc2, acc3, carryx, acc2x, acc3x);
    __syncthreads();

    // ---- FFT2: sk2(n) + i*sk0(n+1) ----
    atomicAdd(&Zf[2 * (q2 & 0xFFF)], sgn(xv0, q2));
    atomicAdd(&Zf[2 * (q0 & 0xFFF) + 1], sgn(xv1, q0));
    __syncthreads();
    s0w(Z, t);
    __builtin_amdgcn_wave_barrier();
    s1w(Z, t, w1b);
    __builtin_amdgcn_wave_barrier();
    s2w(Z, t, w2b);
    __syncthreads();
    s3prod<1>(Z, g, wG, selfp, carry, acc2, acc3, carryx, acc2x, acc3x);
    __syncthreads();

    // ---- FFT3: sk1(n+1) + i*sk2(n+1) ----
    atomicAdd(&Zf[2 * (q1 & 0xFFF)], sgn(xv1, q1));
    atomicAdd(&Zf[2 * (q2 & 0xFFF) + 1], sgn(xv1, q2));
    __syncthreads();
    s0w(Z, t);
    __builtin_amdgcn_wave_barrier();
    s1w(Z, t, w1b);
    __builtin_amdgcn_wave_barrier();
    s2w(Z, t, w2b);
    __syncthreads();
    s3prod<2>(Z, g, wG, selfp, carry, acc2, acc3, carryx, acc2x, acc3x);
    __syncthreads();
  }

  // ---- writeback into this block's replica (bins k = g + 512r) ----
  float* S = ws + (size_t)rep * S_STRIDE;
  #pragma unroll
  for (int r = 0; r < 4; ++r) {
    const int k = g + (r << 9);
    float* p2p = S + ((size_t)(bb * 2 + 0) * 2049 + k) * 2;
    atomicAdd(p2p, acc2[r].x);
    atomicAdd(p2p + 1, acc2[r].y);
    float* p3p = S + ((size_t)(bb * 2 + 1) * 2049 + k) * 2;
    atomicAdd(p3p, acc3[r].x);
    atomicAdd(p3p + 1, acc3[r].y);
  }
  if (g == 0) {
    atomicAdd(S + ((size_t)(bb * 2 + 0) * 2049 + 2048) * 2, acc2x);
    atomicAdd(S + ((size_t)(bb * 2 + 1) * 2049 + 2048) * 2, acc3x);
  }

  const float sc1 = alpha[1] * (1.0f / (float)NPOS);
  atomicAdd(&ws[FO_OFF + (size_t)rep * FO_STRIDE + bb * CH + t], xs * sc1);
}

// ---------------- stage 2: replica-sum + inverse FFT ----------------------
__device__ inline void fft4096_r2(float2* Z, const float2* W, int tid) {
  for (int s = 1; s <= 12; ++s) {
    __syncthreads();
    const int half = 1 << (s - 1);
    const int tsh = 12 - s;
    #pragma unroll
    for (int q = 0; q < 8; ++q) {
      int bidx = tid + q * 256;
      int j = bidx & (half - 1);
      int i1 = ((bidx >> (s - 1)) << s) + j;
      int i2 = i1 + half;
      float2 w = W[j << tsh];
      float2 u = Z[i1];
      float2 v = Z[i2];
      float2 t = cmul(w, v);
      Z[i1] = make_float2(u.x + t.x, u.y + t.y);
      Z[i2] = make_float2(u.x - t.x, u.y - t.y);
    }
  }
  __syncthreads();
}

__global__ __launch_bounds__(256) void cbp_stage2(
    const float* __restrict__ ws_in, const float* __restrict__ alpha,
    float* __restrict__ ws_out) {
  __shared__ float2 Z[DI];
  __shared__ float2 W[DI / 2];
  const int tid = threadIdx.x;

  for (int r = tid; r < DI / 2; r += 256) {
    float ang = 1.5339807878856412e-3f * (float)r;  // +2pi/4096*r (inverse)
    float sv, cv;
    sincosf(ang, &sv, &cv);
    W[r] = make_float2(cv, sv);
  }

  const int b = blockIdx.x >> 1;
  const int t = blockIdx.x & 1;
  const float* Sp = ws_in + ((size_t)(b * 2 + t) * 2049) * 2;

  for (int k = tid; k <= 2048; k += 256) {
    float re = 0.f, im = 0.f;
    #pragma unroll
    for (int rp = 0; rp < REP; ++rp) {
      re += Sp[(size_t)rp * S_STRIDE + k * 2];
      im += Sp[(size_t)rp * S_STRIDE + k * 2 + 1];
    }
    Z[__brev((unsigned)k) >> 20] = make_float2(re, im);
    if (k > 0 && k < 2048) {
      Z[__brev((unsigned)(DI - k)) >> 20] = make_float2(re, -im);
    }
  }
  fft4096_r2(Z, W, tid);

  const float scale = alpha[2 + t] / ((float)DI * (float)NPOS);
  float* out = ws_out + PH_OFF + (size_t)(b * 2 + t) * DI;
  for (int d = tid; d < DI; d += 256) out[d] = Z[d].x * scale;
}

// ---------------- stage 3: assemble phi, signed sqrt, L2 norm -------------
__global__ __launch_bounds__(256) void cbp_stage3(
    const float* __restrict__ ws_in, const float* __restrict__ alpha,
    float* __restrict__ out) {
  __shared__ float red[4];
  const int b = blockIdx.x;
  const int tid = threadIdx.x;
  const float a0 = alpha[0];

  float w[35];
  float ssum = 0.f;
  #pragma unroll
  for (int j = 0; j < 35; ++j) {
    const int idx = tid + j * 256;
    float wv = 0.f;
    if (idx < PHI_LEN) {
      float v;
      if (idx == 0) {
        v = a0;
      } else if (idx <= 512) {
        v = 0.f;
        #pragma unroll
        for (int rp = 0; rp < REP; ++rp)
          v += ws_in[FO_OFF + (size_t)rp * FO_STRIDE + b * CH + (idx - 1)];
      } else {
        v = ws_in[PH_OFF + (size_t)b * 2 * DI + (idx - 513)];
      }
      float sq = sqrtf(fabsf(v) + 1e-12f);
      wv = (v > 0.f) ? sq : ((v < 0.f) ? -sq : 0.f);
    }
    w[j] = wv;
    ssum += wv * wv;
  }
  for (int off = 32; off > 0; off >>= 1) ssum += __shfl_down(ssum, off);
  if ((tid & 63) == 0) red[tid >> 6] = ssum;
  __syncthreads();
  const float tot = red[0] + red[1] + red[2] + red[3];
  const float inv = 1.0f / sqrtf(tot);

  #pragma unroll
  for (int j = 0; j < 35; ++j) {
    const int idx = tid + j * 256;
    if (idx < PHI_LEN) out[(size_t)b * PHI_LEN + idx] = w[j] * inv;
  }
}

extern "C" void kernel_launch(void* const* d_in, const int* in_sizes, int n_in,
                              void* d_out, int out_size, void* d_ws,
                              size_t ws_size, hipStream_t stream) {
  const float* x = (const float*)d_in[0];
  const float* alpha = (const float*)d_in[1];
  const int* h_idx = (const int*)d_in[2];
  const int* s_bits = (const int*)d_in[3];
  float* out = (float*)d_out;
  float* ws = (float*)d_ws;

  hipMemsetAsync(d_ws, 0, (size_t)ZERO_FLOATS * sizeof(float), stream);

  cbp_stage1<<<dim3(BATCH * CHUNKS), dim3(512), 0, stream>>>(x, alpha, h_idx,
                                                             s_bits, ws);
  cbp_stage2<<<dim3(BATCH * 2), dim3(256), 0, stream>>>(ws, alpha, ws);
  cbp_stage3<<<dim3(BATCH), dim3(256), 0, stream>>>(ws, alpha, out);
}

// Round 11
// 223.845 us; speedup vs baseline: 1.0575x; 1.0575x over previous
//
#include <hip/hip_runtime.h>

#define BATCH 8
#define NPOS 784          // H*W per batch
#define CH 512
#define DI 4096
#define PPC 8             // positions per chunk (multiple of 2)
#define CHUNKS (NPOS / PPC)   // 98 -> 784 blocks
#define PHI_LEN 8705      // 1 + 512 + 2*4096
#define REP 16            // accumulator replicas
#define S_STRIDE (BATCH * 2 * 2049 * 2)
#define S_FLOATS (REP * S_STRIDE)
#define FO_OFF S_FLOATS
#define FO_STRIDE (BATCH * CH)
#define FO_FLOATS (REP * FO_STRIDE)
#define PH_OFF (FO_OFF + FO_FLOATS)
#define ZERO_FLOATS (S_FLOATS + FO_FLOATS)

__device__ __forceinline__ float2 cmul(float2 a, float2 b) {
  return make_float2(a.x * b.x - a.y * b.y, a.x * b.y + a.y * b.x);
}
__device__ __forceinline__ float2 f2add(float2 a, float2 b) {
  return make_float2(a.x + b.x, a.y + b.y);
}
__device__ __forceinline__ float2 f2sub(float2 a, float2 b) {
  return make_float2(a.x - b.x, a.y - b.y);
}

__device__ __forceinline__ void dft4(float2& a, float2& b, float2& c, float2& d) {
  float t0x = a.x + c.x, t0y = a.y + c.y;
  float t1x = a.x - c.x, t1y = a.y - c.y;
  float t2x = b.x + d.x, t2y = b.y + d.y;
  float t3x = b.x - d.x, t3y = b.y - d.y;
  a = make_float2(t0x + t2x, t0y + t2y);
  c = make_float2(t0x - t2x, t0y - t2y);
  b = make_float2(t1x + t3y, t1y - t3x);   // t1 - i*t3
  d = make_float2(t1x - t3y, t1y + t3x);   // t1 + i*t3
}

__device__ __forceinline__ void dft8(float2 v[8]) {
  float2 e0 = v[0], e1 = v[2], e2 = v[4], e3 = v[6];
  dft4(e0, e1, e2, e3);
  float2 o0 = v[1], o1 = v[3], o2 = v[5], o3 = v[7];
  dft4(o0, o1, o2, o3);
  const float r = 0.70710678118654752f;
  o1 = make_float2(r * (o1.x + o1.y), r * (o1.y - o1.x));   // *w8^1
  o2 = make_float2(o2.y, -o2.x);                            // *-i
  o3 = make_float2(r * (o3.y - o3.x), -r * (o3.x + o3.y));  // *w8^3
  v[0] = f2add(e0, o0); v[4] = f2sub(e0, o0);
  v[1] = f2add(e1, o1); v[5] = f2sub(e1, o1);
  v[2] = f2add(e2, o2); v[6] = f2sub(e2, o2);
  v[3] = f2add(e3, o3); v[7] = f2sub(e3, o3);
}

__device__ __forceinline__ void twiddle8(float2 v[8], float2 w) {
  float2 w2 = cmul(w, w);
  float2 w3 = cmul(w2, w);
  float2 w4 = cmul(w2, w2);
  v[1] = cmul(v[1], w);
  v[2] = cmul(v[2], w2);
  v[3] = cmul(v[3], w3);
  v[4] = cmul(v[4], w4);
  v[5] = cmul(v[5], cmul(w4, w));
  v[6] = cmul(v[6], cmul(w4, w2));
  v[7] = cmul(v[7], cmul(w4, w3));
}

// ---- radix-8 stages on butterfly index b; phys(i) = i ^ ((i>>4)&15).
// Stages 0-2 touch only segment floor(b/64)*512..+512 (wave-local property).
__device__ __forceinline__ void s0w(float2* Z, int b) {
  const int base = b << 3;
  const int m0 = (b >> 1) & 15;
  float2 v[8];
  #pragma unroll
  for (int u = 0; u < 8; ++u) v[u] = Z[(base + u) ^ m0];
  dft8(v);
  #pragma unroll
  for (int k = 0; k < 8; ++k) Z[(base + k) ^ m0] = v[k];
}
__device__ __forceinline__ void s1w(float2* Z, int b, float2 w) {
  const int base = ((b >> 3) << 6) + (b & 7);
  const int g4 = (b >> 3) << 2;
  float2 v[8];
  #pragma unroll
  for (int u = 0; u < 8; ++u)
    v[u] = Z[(base + (u << 3)) ^ ((g4 + (u >> 1)) & 15)];
  twiddle8(v, w);
  dft8(v);
  #pragma unroll
  for (int k = 0; k < 8; ++k)
    Z[(base + (k << 3)) ^ ((g4 + (k >> 1)) & 15)] = v[k];
}
__device__ __forceinline__ void s2w(float2* Z, int b, float2 w) {
  const int base = ((b >> 6) << 9) + (b & 63);
  const int jh = (b & 63) >> 4;
  float2 v[8];
  #pragma unroll
  for (int u = 0; u < 8; ++u)
    v[u] = Z[(base + (u << 6)) ^ (((u << 2) + jh) & 15)];
  twiddle8(v, w);
  dft8(v);
  #pragma unroll
  for (int k = 0; k < 8; ++k)
    Z[(base + (k << 6)) ^ (((k << 2) + jh) & 15)] = v[k];
}
__device__ __forceinline__ void s3w(float2* Z, int b, float2 w) {
  const int m3 = (b >> 4) & 15;
  float2 v[8];
  #pragma unroll
  for (int u = 0; u < 8; ++u) v[u] = Z[(b + (u << 9)) ^ m3];
  twiddle8(v, w);
  dft8(v);
  #pragma unroll
  for (int k = 0; k < 8; ++k) Z[(b + (k << 9)) ^ m3] = v[k];
}

// Hermitian pair product + chain update.
template <int MODE>
__device__ __forceinline__ void prodpair(float2 Zk, float2 Zm, float2& carry,
                                         float2& acc2, float2& acc3) {
  float2 E = make_float2(0.5f * (Zk.x + Zm.x), 0.5f * (Zk.y - Zm.y));
  float2 O = make_float2(0.5f * (Zk.y + Zm.y), -0.5f * (Zk.x - Zm.x));
  if (MODE == 0) {
    float2 P = cmul(E, O);
    carry = P;
    acc2.x += P.x; acc2.y += P.y;
  } else if (MODE == 1) {
    float2 P3 = cmul(carry, E);
    acc3.x += P3.x; acc3.y += P3.y;
    carry = O;
  } else {
    float2 P = cmul(carry, E);
    acc2.x += P.x; acc2.y += P.y;
    float2 P3 = cmul(P, O);
    acc3.x += P3.x; acc3.y += P3.y;
  }
}
template <int MODE>
__device__ __forceinline__ void nyq(float2 Zq, float& carryx, float& acc2x,
                                    float& acc3x) {
  if (MODE == 0) { carryx = Zq.x * Zq.y; acc2x += carryx; }
  else if (MODE == 1) { acc3x += carryx * Zq.x; carryx = Zq.y; }
  else { float tt = carryx * Zq.x; acc2x += tt; acc3x += tt * Zq.y; }
}

// product over this thread's 8 bins; reads + zeroes Z.
template <int MODE>
__device__ __forceinline__ void product_phase(float2* Z, int t,
                                              float2 carry[8], float2 acc2[8],
                                              float2 acc3[8], float& carryx,
                                              float& acc2x, float& acc3x) {
  const int mask3 = (t >> 4) & 15;
  #pragma unroll
  for (int jj = 0; jj < 8; ++jj) {
    const int k = t + (jj << 8);
    const int ak = k ^ mask3;
    const int m = (DI - k) & (DI - 1);
    const int am = m ^ ((m >> 4) & 15);
    float2 Zk = Z[ak], Zm = Z[am];
    Z[ak] = make_float2(0.f, 0.f);
    Z[am] = make_float2(0.f, 0.f);
    prodpair<MODE>(Zk, Zm, carry[jj], acc2[jj], acc3[jj]);
  }
  if (t == 0) {
    float2 Zq = Z[2048];
    Z[2048] = make_float2(0.f, 0.f);
    nyq<MODE>(Zq, carryx, acc2x, acc3x);
  }
}

__global__ __launch_bounds__(256) void cbp_stage1(
    const float* __restrict__ x, const float* __restrict__ alpha,
    const int* __restrict__ h_idx, const int* __restrict__ s_bits,
    float* __restrict__ ws) {
  __shared__ float2 Z[DI];
  float* Zf = (float*)Z;
  const int t = threadIdx.x;
  const int bb = blockIdx.x / CHUNKS;
  const int ch = blockIdx.x % CHUNKS;
  const int rep = blockIdx.x & (REP - 1);

  // hash -> phys(digitrev8(h)) | sign<<12 ; two channels packed per int
  auto mapq = [](int h, int s) {
    int r = ((h & 7) << 9) | (((h >> 3) & 7) << 6) | (((h >> 6) & 7) << 3) |
            (h >> 9);
    return (r ^ ((r >> 4) & 15)) | ((s ^ 1) << 12);
  };
  auto sgn = [](float v, int q) {
    return __int_as_float(__float_as_int(v) ^ ((q & 0x1000) << 19));
  };
  const int c0 = t * 2, c1 = c0 + 1;
  const int qp0 = mapq(h_idx[c0], s_bits[c0]) |
                  (mapq(h_idx[c1], s_bits[c1]) << 13);
  const int qp1 = mapq(h_idx[CH + c0], s_bits[CH + c0]) |
                  (mapq(h_idx[CH + c1], s_bits[CH + c1]) << 13);
  const int qp2 = mapq(h_idx[2 * CH + c0], s_bits[2 * CH + c0]) |
                  (mapq(h_idx[2 * CH + c1], s_bits[2 * CH + c1]) << 13);

  // persistent twiddles; butterflies t and t+256 share w1b/w2b (256%64==0)
  float sv_, cv_;
  __sincosf(-9.8174770424681038e-2f * (float)(t & 7), &sv_, &cv_);   // -2pi/64*j
  const float2 w1b = make_float2(cv_, sv_);
  __sincosf(-1.2271846303085130e-2f * (float)(t & 63), &sv_, &cv_);  // -2pi/512*j
  const float2 w2b = make_float2(cv_, sv_);
  __sincosf(-1.5339807878856412e-3f * (float)t, &sv_, &cv_);         // -2pi/4096*t
  const float2 w3b = make_float2(cv_, sv_);
  // w4096^256 = e^{-i pi/8}
  const float2 W256 = make_float2(0.92387953251128674f, -0.38268343236508977f);

  float2 acc2[8], acc3[8], carry[8];
  #pragma unroll
  for (int j = 0; j < 8; ++j) {
    acc2[j] = make_float2(0.f, 0.f);
    acc3[j] = make_float2(0.f, 0.f);
  }
  float acc2x = 0.f, acc3x = 0.f, carryx = 0.f;
  float xsa = 0.f, xsb = 0.f;

  #pragma unroll
  for (int q = 0; q < 16; ++q) Z[t + (q << 8)] = make_float2(0.f, 0.f);
  __syncthreads();

  #pragma unroll 1
  for (int ip = 0; ip < PPC / 2; ++ip) {
    const int n0 = bb * NPOS + ch * PPC + ip * 2;
    const float2 xv0 = *(const float2*)(x + (size_t)n0 * CH + c0);
    const float2 xv1 = *(const float2*)(x + (size_t)(n0 + 1) * CH + c0);
    xsa += xv0.x + xv1.x;
    xsb += xv0.y + xv1.y;

    #pragma unroll 1
    for (int f = 0; f < 3; ++f) {
      // scatter: f=0 -> sk0(n)+i*sk1(n); f=1 -> sk2(n)+i*sk0(n+1);
      //          f=2 -> sk1(n+1)+i*sk2(n+1)
      {
        const int qpr = (f == 0) ? qp0 : (f == 1) ? qp2 : qp1;
        const int qpi = (f == 0) ? qp1 : (f == 1) ? qp0 : qp2;
        const float vr0 = (f == 2) ? xv1.x : xv0.x;
        const float vr1 = (f == 2) ? xv1.y : xv0.y;
        const float vi0 = (f == 0) ? xv0.x : xv1.x;
        const float vi1 = (f == 0) ? xv0.y : xv1.y;
        const int qa = qpr & 0x1FFF, qb = (qpr >> 13) & 0x1FFF;
        const int ra = qpi & 0x1FFF, rb = (qpi >> 13) & 0x1FFF;
        atomicAdd(&Zf[2 * (qa & 0xFFF)], sgn(vr0, qa));
        atomicAdd(&Zf[2 * (qb & 0xFFF)], sgn(vr1, qb));
        atomicAdd(&Zf[2 * (ra & 0xFFF) + 1], sgn(vi0, ra));
        atomicAdd(&Zf[2 * (rb & 0xFFF) + 1], sgn(vi1, rb));
      }
      __syncthreads();
      // stages 0-2: wave-local (wave v owns segments v and v+4)
      #pragma unroll 1
      for (int h = 0; h < 2; ++h) s0w(Z, t + (h << 8));
      __builtin_amdgcn_wave_barrier();
      #pragma unroll 1
      for (int h = 0; h < 2; ++h) s1w(Z, t + (h << 8), w1b);
      __builtin_amdgcn_wave_barrier();
      #pragma unroll 1
      for (int h = 0; h < 2; ++h) s2w(Z, t + (h << 8), w2b);
      __syncthreads();
      // stage 3 (cross-segment)
      #pragma unroll 1
      for (int h = 0; h < 2; ++h)
        s3w(Z, t + (h << 8), h ? cmul(w3b, W256) : w3b);
      __syncthreads();
      if (f == 0)
        product_phase<0>(Z, t, carry, acc2, acc3, carryx, acc2x, acc3x);
      else if (f == 1)
        product_phase<1>(Z, t, carry, acc2, acc3, carryx, acc2x, acc3x);
      else
        product_phase<2>(Z, t, carry, acc2, acc3, carryx, acc2x, acc3x);
      __syncthreads();
    }
  }

  // ---- writeback into this block's replica ----
  float* S = ws + (size_t)rep * S_STRIDE;
  #pragma unroll
  for (int jj = 0; jj < 8; ++jj) {
    const int k = t + (jj << 8);
    float* p2p = S + ((size_t)(bb * 2 + 0) * 2049 + k) * 2;
    atomicAdd(p2p, acc2[jj].x);
    atomicAdd(p2p + 1, acc2[jj].y);
    float* p3p = S + ((size_t)(bb * 2 + 1) * 2049 + k) * 2;
    atomicAdd(p3p, acc3[jj].x);
    atomicAdd(p3p + 1, acc3[jj].y);
  }
  if (t == 0) {
    atomicAdd(S + ((size_t)(bb * 2 + 0) * 2049 + 2048) * 2, acc2x);
    atomicAdd(S + ((size_t)(bb * 2 + 1) * 2049 + 2048) * 2, acc3x);
  }

  const float sc1 = alpha[1] * (1.0f / (float)NPOS);
  atomicAdd(&ws[FO_OFF + (size_t)rep * FO_STRIDE + bb * CH + c0], xsa * sc1);
  atomicAdd(&ws[FO_OFF + (size_t)rep * FO_STRIDE + bb * CH + c1], xsb * sc1);
}

// ---------------- stage 2: replica-sum + inverse FFT ----------------------
__device__ inline void fft4096_r2(float2* Z, const float2* W, int tid) {
  for (int s = 1; s <= 12; ++s) {
    __syncthreads();
    const int half = 1 << (s - 1);
    const int tsh = 12 - s;
    #pragma unroll
    for (int q = 0; q < 8; ++q) {
      int bidx = tid + q * 256;
      int j = bidx & (half - 1);
      int i1 = ((bidx >> (s - 1)) << s) + j;
      int i2 = i1 + half;
      float2 w = W[j << tsh];
      float2 u = Z[i1];
      float2 v = Z[i2];
      float2 t = cmul(w, v);
      Z[i1] = make_float2(u.x + t.x, u.y + t.y);
      Z[i2] = make_float2(u.x - t.x, u.y - t.y);
    }
  }
  __syncthreads();
}

__global__ __launch_bounds__(256) void cbp_stage2(
    const float* __restrict__ ws_in, const float* __restrict__ alpha,
    float* __restrict__ ws_out) {
  __shared__ float2 Z[DI];
  __shared__ float2 W[DI / 2];
  const int tid = threadIdx.x;

  for (int r = tid; r < DI / 2; r += 256) {
    float ang = 1.5339807878856412e-3f * (float)r;  // +2pi/4096*r (inverse)
    float sv, cv;
    sincosf(ang, &sv, &cv);
    W[r] = make_float2(cv, sv);
  }

  const int b = blockIdx.x >> 1;
  const int t = blockIdx.x & 1;
  const float* Sp = ws_in + ((size_t)(b * 2 + t) * 2049) * 2;

  for (int k = tid; k <= 2048; k += 256) {
    float re = 0.f, im = 0.f;
    #pragma unroll
    for (int rp = 0; rp < REP; ++rp) {
      re += Sp[(size_t)rp * S_STRIDE + k * 2];
      im += Sp[(size_t)rp * S_STRIDE + k * 2 + 1];
    }
    Z[__brev((unsigned)k) >> 20] = make_float2(re, im);
    if (k > 0 && k < 2048) {
      Z[__brev((unsigned)(DI - k)) >> 20] = make_float2(re, -im);
    }
  }
  fft4096_r2(Z, W, tid);

  const float scale = alpha[2 + t] / ((float)DI * (float)NPOS);
  float* out = ws_out + PH_OFF + (size_t)(b * 2 + t) * DI;
  for (int d = tid; d < DI; d += 256) out[d] = Z[d].x * scale;
}

// ---------------- stage 3: assemble phi, signed sqrt, L2 norm -------------
__global__ __launch_bounds__(256) void cbp_stage3(
    const float* __restrict__ ws_in, const float* __restrict__ alpha,
    float* __restrict__ out) {
  __shared__ float red[4];
  const int b = blockIdx.x;
  const int tid = threadIdx.x;
  const float a0 = alpha[0];

  float w[35];
  float ssum = 0.f;
  #pragma unroll
  for (int j = 0; j < 35; ++j) {
    const int idx = tid + j * 256;
    float wv = 0.f;
    if (idx < PHI_LEN) {
      float v;
      if (idx == 0) {
        v = a0;
      } else if (idx <= 512) {
        v = 0.f;
        #pragma unroll
        for (int rp = 0; rp < REP; ++rp)
          v += ws_in[FO_OFF + (size_t)rp * FO_STRIDE + b * CH + (idx - 1)];
      } else {
        v = ws_in[PH_OFF + (size_t)b * 2 * DI + (idx - 513)];
      }
      float sq = sqrtf(fabsf(v) + 1e-12f);
      wv = (v > 0.f) ? sq : ((v < 0.f) ? -sq : 0.f);
    }
    w[j] = wv;
    ssum += wv * wv;
  }
  for (int off = 32; off > 0; off >>= 1) ssum += __shfl_down(ssum, off);
  if ((tid & 63) == 0) red[tid >> 6] = ssum;
  __syncthreads();
  const float tot = red[0] + red[1] + red[2] + red[3];
  const float inv = 1.0f / sqrtf(tot);

  #pragma unroll
  for (int j = 0; j < 35; ++j) {
    const int idx = tid + j * 256;
    if (idx < PHI_LEN) out[(size_t)b * PHI_LEN + idx] = w[j] * inv;
  }
}

extern "C" void kernel_launch(void* const* d_in, const int* in_sizes, int n_in,
                              void* d_out, int out_size, void* d_ws,
                              size_t ws_size, hipStream_t stream) {
  const float* x = (const float*)d_in[0];
  const float* alpha = (const float*)d_in[1];
  const int* h_idx = (const int*)d_in[2];
  const int* s_bits = (const int*)d_in[3];
  float* out = (float*)d_out;
  float* ws = (float*)d_ws;

  hipMemsetAsync(d_ws, 0, (size_t)ZERO_FLOATS * sizeof(float), stream);

  cbp_stage1<<<dim3(BATCH * CHUNKS), dim3(256), 0, stream>>>(x, alpha, h_idx,
                                                             s_bits, ws);
  cbp_stage2<<<dim3(BATCH * 2), dim3(256), 0, stream>>>(ws, alpha, ws);
  cbp_stage3<<<dim3(BATCH), dim3(256), 0, stream>>>(ws, alpha, out);
}